// Round 7
// baseline (22640.697 us; speedup 1.0000x reference)
//
#include <hip/hip_runtime.h>
#include <math.h>

#define BB 4096
#define TT 48
#define DD 32
#define HH 256
#define LL 128
#define HID 256
#define EE 8
#define NHZ 48
#define NS 12             // RK4 macro steps (dense-output Hermite between knots)
#define NTEMB (2*NS+1)    // 25 precomputed time-embeddings
#define ROWS 8            // batch rows per block (512 blocks = 2 blocks/CU)

__device__ __forceinline__ float sigm_f(float x) {
    return 1.0f / (1.0f + __expf(-x));
}
__device__ __forceinline__ float tanh_f(float x) {
    x = fminf(fmaxf(x, -15.0f), 15.0f);
    float e = __expf(2.0f * x);
    return (e - 1.0f) / (e + 1.0f);
}
__device__ __forceinline__ float4 axpy4(float s, float4 a, float4 z) {
    return make_float4(fmaf(s, a.x, z.x), fmaf(s, a.y, z.y),
                       fmaf(s, a.z, z.z), fmaf(s, a.w, z.w));
}

// ---------------- prep kernels ----------------
// pack4: src [OUT][IN] row-major -> dst[(k>>2)*OUT + o] float4 = w[o][4k..4k+3]

__global__ void pack4_k(const float* __restrict__ src, float* __restrict__ dst, int OUT, int IN) {
    int i = blockIdx.x * 256 + threadIdx.x;
    if (i < OUT * IN) {
        int o = i / IN, k = i % IN;
        dst[((k >> 2) * OUT + o) * 4 + (k & 3)] = src[i];
    }
}

__global__ void temb_k(const float* __restrict__ tproj_w, const float* __restrict__ tproj_b,
                       float* __restrict__ tembs) {
    int i = blockIdx.x * 64 + threadIdx.x;
    if (i >= NTEMB) return;
    float t = (float)i / (float)(2 * NS);
    const float PI = 3.14159265358979323846f;
    float emb[8];
    #pragma unroll
    for (int m = 0; m < 4; ++m) {
        float pos = t * (float)(m + 1) * PI;
        emb[m]     = sinf(pos);
        emb[4 + m] = cosf(pos);
    }
    #pragma unroll
    for (int o = 0; o < 8; ++o) {
        float a = tproj_b[o];
        #pragma unroll
        for (int k = 0; k < 8; ++k) a = fmaf(tproj_w[o * 8 + k], emb[k], a);
        tembs[i * 8 + o] = a;
    }
}

// ---------------- GRU encoder (+ fused z0 projection) ----------------
// 8 rows/block, 512 threads, 512 blocks (2 blocks/CU). j = tid&255 owns gate
// triplet col j; group tid>>8 owns rows group*4..+3. (512,2) = proven no-spill.

__global__ __launch_bounds__(512, 2) void gru_k(
    const float* __restrict__ Xp, const float* __restrict__ Mp,
    const float* __restrict__ w_ihp,   // packed [16][768][4]
    const float* __restrict__ w_hhp,   // packed [64][768][4]
    const float* __restrict__ b_ih, const float* __restrict__ b_hh,
    const float* __restrict__ z0_wp,   // packed [64][256][4]
    const float* __restrict__ z0_b,
    float* __restrict__ out_mean, float* __restrict__ out_lv) {

    __shared__ __align__(16) float h[ROWS * HH];   // 8KB
    __shared__ __align__(16) float u[ROWS * 64];   // 2KB
    __shared__ float obs[ROWS];

    int tid = threadIdx.x, blk = blockIdx.x;
    int j = tid & 255, rb = (tid >> 8) * 4;

    const float4* hq  = (const float4*)h;
    const float4* uq  = (const float4*)u;
    const float4* wih = (const float4*)w_ihp;
    const float4* whh = (const float4*)w_hhp;
    const float4* z0q = (const float4*)z0_wp;

    for (int e = tid; e < ROWS * HH; e += 512) h[e] = 0.0f;

    float brz0 = b_ih[j]       + b_hh[j];
    float brz1 = b_ih[256 + j] + b_hh[256 + j];
    float bin_ = b_ih[512 + j];
    float bhn_ = b_hh[512 + j];
    __syncthreads();

    for (int t = TT - 1; t >= 0; --t) {
        if (tid < 16 * ROWS) {
            int r = tid >> 4, c4 = tid & 15;
            const float* base = (c4 < 8 ? Xp : Mp) + (size_t)(blk * ROWS + r) * (TT * DD) + t * DD;
            ((float4*)u)[tid] = ((const float4*)base)[c4 & 7];
        }
        __syncthreads();
        if (tid < ROWS) {
            float sm = 0.0f;
            #pragma unroll
            for (int i = 8; i < 16; ++i) {
                float4 v = uq[tid * 16 + i];
                sm += v.x + v.y + v.z + v.w;
            }
            obs[tid] = (sm > 0.0f) ? 1.0f : 0.0f;
        }

        float ar[4], az[4], an[4], ah[4];
        #pragma unroll
        for (int r = 0; r < 4; ++r) { ar[r] = brz0; az[r] = brz1; an[r] = bin_; ah[r] = bhn_; }

        // input contribution: 16 packed k4 over 64 inputs
        for (int k4 = 0; k4 < 16; ++k4) {
            float4 wr = wih[k4 * 768 + j];
            float4 wz = wih[k4 * 768 + 256 + j];
            float4 wn = wih[k4 * 768 + 512 + j];
            #pragma unroll
            for (int r = 0; r < 4; ++r) {
                float4 v = uq[(rb + r) * 16 + k4];
                ar[r] = fmaf(wr.x, v.x, ar[r]); az[r] = fmaf(wz.x, v.x, az[r]); an[r] = fmaf(wn.x, v.x, an[r]);
                ar[r] = fmaf(wr.y, v.y, ar[r]); az[r] = fmaf(wz.y, v.y, az[r]); an[r] = fmaf(wn.y, v.y, an[r]);
                ar[r] = fmaf(wr.z, v.z, ar[r]); az[r] = fmaf(wz.z, v.z, az[r]); an[r] = fmaf(wn.z, v.z, an[r]);
                ar[r] = fmaf(wr.w, v.w, ar[r]); az[r] = fmaf(wz.w, v.w, az[r]); an[r] = fmaf(wn.w, v.w, an[r]);
            }
        }
        // hidden contribution: 64 packed k4 over 256
        for (int k4 = 0; k4 < 64; ++k4) {
            float4 wr = whh[k4 * 768 + j];
            float4 wz = whh[k4 * 768 + 256 + j];
            float4 wn = whh[k4 * 768 + 512 + j];
            #pragma unroll
            for (int r = 0; r < 4; ++r) {
                float4 v = hq[(rb + r) * 64 + k4];
                ar[r] = fmaf(wr.x, v.x, ar[r]); az[r] = fmaf(wz.x, v.x, az[r]); ah[r] = fmaf(wn.x, v.x, ah[r]);
                ar[r] = fmaf(wr.y, v.y, ar[r]); az[r] = fmaf(wz.y, v.y, az[r]); ah[r] = fmaf(wn.y, v.y, ah[r]);
                ar[r] = fmaf(wr.z, v.z, ar[r]); az[r] = fmaf(wz.z, v.z, az[r]); ah[r] = fmaf(wn.z, v.z, ah[r]);
                ar[r] = fmaf(wr.w, v.w, ar[r]); az[r] = fmaf(wz.w, v.w, az[r]); ah[r] = fmaf(wn.w, v.w, ah[r]);
            }
        }

        float hnew[4], hold[4];
        #pragma unroll
        for (int r = 0; r < 4; ++r) {
            float rg = sigm_f(ar[r]);
            float zg = sigm_f(az[r]);
            float n  = tanh_f(an[r] + rg * ah[r]);
            float hv = h[(rb + r) * HH + j];
            hold[r] = hv;
            hnew[r] = (1.0f - zg) * n + zg * hv;
        }
        __syncthreads();
        #pragma unroll
        for (int r = 0; r < 4; ++r) {
            float o = obs[rb + r];
            h[(rb + r) * HH + j] = o * hnew[r] + (1.0f - o) * hold[r];
        }
        __syncthreads();
    }

    // fused z0 projection
    float zr_[4];
    #pragma unroll
    for (int r = 0; r < 4; ++r) zr_[r] = z0_b[j];
    for (int k4 = 0; k4 < 64; ++k4) {
        float4 w = z0q[k4 * 256 + j];
        #pragma unroll
        for (int r = 0; r < 4; ++r) {
            float4 v = hq[(rb + r) * 64 + k4];
            zr_[r] = fmaf(w.x, v.x, zr_[r]);
            zr_[r] = fmaf(w.y, v.y, zr_[r]);
            zr_[r] = fmaf(w.z, v.z, zr_[r]);
            zr_[r] = fmaf(w.w, v.w, zr_[r]);
        }
    }
    int row0 = blk * ROWS + rb;
    if (j < 128) {
        #pragma unroll
        for (int r = 0; r < 4; ++r) out_mean[(row0 + r) * LL + j] = zr_[r];
    } else {
        #pragma unroll
        for (int r = 0; r < 4; ++r) out_lv[(row0 + r) * LL + (j - 128)] = zr_[r];
    }
}

// ---------------- ODE dynamics eval: 512 threads, 8 rows ----------------

__device__ __forceinline__ void ode_f8(
    const float* __restrict__ in, float* __restrict__ h1, float* __restrict__ h2,
    float* __restrict__ out,
    const float4* __restrict__ w1q, const float4* __restrict__ w2q, const float4* __restrict__ w3q,
    const float* __restrict__ temb,   // 8 floats (global, L2)
    float b1j, float b2j, float b3o, int tid) {

    int j  = tid & 255;  int rb = (tid >> 8) * 4;   // phases A,B: 4 rows each of 2 groups
    int od = tid & 127;  int rc = (tid >> 7) * 2;   // phase C: 2 rows each of 4 groups

    const float4* inq = (const float4*)in;
    const float4* h1q = (const float4*)h1;
    const float4* h2q = (const float4*)h2;

    // phase A: h1 = tanh([z,temb] @ w1.T + b1)
    float4 wt0 = w1q[32 * 256 + j];
    float4 wt1 = w1q[33 * 256 + j];
    float tacc = b1j;
    tacc = fmaf(wt0.x, temb[0], tacc); tacc = fmaf(wt0.y, temb[1], tacc);
    tacc = fmaf(wt0.z, temb[2], tacc); tacc = fmaf(wt0.w, temb[3], tacc);
    tacc = fmaf(wt1.x, temb[4], tacc); tacc = fmaf(wt1.y, temb[5], tacc);
    tacc = fmaf(wt1.z, temb[6], tacc); tacc = fmaf(wt1.w, temb[7], tacc);
    float a[4];
    #pragma unroll
    for (int r = 0; r < 4; ++r) a[r] = tacc;
    for (int k4 = 0; k4 < 32; ++k4) {
        float4 w = w1q[k4 * 256 + j];
        #pragma unroll
        for (int r = 0; r < 4; ++r) {
            float4 v = inq[(rb + r) * 32 + k4];
            a[r] = fmaf(w.x, v.x, a[r]); a[r] = fmaf(w.y, v.y, a[r]);
            a[r] = fmaf(w.z, v.z, a[r]); a[r] = fmaf(w.w, v.w, a[r]);
        }
    }
    #pragma unroll
    for (int r = 0; r < 4; ++r) h1[(rb + r) * HID + j] = tanh_f(a[r]);
    __syncthreads();

    // phase B: h2 = tanh(h1 @ w2.T + b2)
    float c[4];
    #pragma unroll
    for (int r = 0; r < 4; ++r) c[r] = b2j;
    for (int k4 = 0; k4 < 64; ++k4) {
        float4 w = w2q[k4 * 256 + j];
        #pragma unroll
        for (int r = 0; r < 4; ++r) {
            float4 v = h1q[(rb + r) * 64 + k4];
            c[r] = fmaf(w.x, v.x, c[r]); c[r] = fmaf(w.y, v.y, c[r]);
            c[r] = fmaf(w.z, v.z, c[r]); c[r] = fmaf(w.w, v.w, c[r]);
        }
    }
    #pragma unroll
    for (int r = 0; r < 4; ++r) h2[(rb + r) * HID + j] = tanh_f(c[r]);
    __syncthreads();

    // phase C: out = h2 @ w3.T + b3 (2 rows per thread at out-dim od)
    float d[2];
    #pragma unroll
    for (int r = 0; r < 2; ++r) d[r] = b3o;
    for (int k4 = 0; k4 < 64; ++k4) {
        float4 w = w3q[k4 * 128 + od];
        #pragma unroll
        for (int r = 0; r < 2; ++r) {
            float4 v = h2q[(rc + r) * 64 + k4];
            d[r] = fmaf(w.x, v.x, d[r]); d[r] = fmaf(w.y, v.y, d[r]);
            d[r] = fmaf(w.z, v.z, d[r]); d[r] = fmaf(w.w, v.w, d[r]);
        }
    }
    #pragma unroll
    for (int r = 0; r < 2; ++r) out[(rc + r) * LL + od] = d[r];
    __syncthreads();
}

// ---------------- ODE (12-step RK4 + Hermite dense output) + head ----------------
// 8 rows/block, 512 threads, 512 blocks. LDS 52KB -> 2 blocks/CU.

__global__ __launch_bounds__(512, 2) void ode_head_k(
    const float* __restrict__ zinit,
    const float* __restrict__ w1p, const float* __restrict__ w2p, const float* __restrict__ w3p,
    const float* __restrict__ b1, const float* __restrict__ b2, const float* __restrict__ b3,
    const float* __restrict__ tembs,
    const float* __restrict__ shw1g, const float* __restrict__ shb1,
    const float* __restrict__ shw2, const float* __restrict__ shb2,
    float* __restrict__ out_haz, float* __restrict__ out_surv, float* __restrict__ out_pg) {

    __shared__ __align__(16) float bufA [ROWS * LL];   // 4KB  (z at knot s)
    __shared__ __align__(16) float bufB [ROWS * LL];   // 4KB  (z at knot s+1)
    __shared__ __align__(16) float bufFP[ROWS * LL];   // 4KB  (f at knot s)
    __shared__ __align__(16) float bufFN[ROWS * LL];   // 4KB  (f at knot s+1 / scratch)
    __shared__ __align__(16) float ztl  [ROWS * LL];   // 4KB  (stage state / z-theta)
    __shared__ __align__(16) float hb1  [ROWS * HID];  // 8KB
    __shared__ __align__(16) float hb2  [ROWS * HID];  // 8KB
    __shared__ __align__(16) float w1h  [32 * 128];    // 16KB head W1 packed [k4][unit][4]

    int tid = threadIdx.x, blk = blockIdx.x;
    int j = tid & 255, od = tid & 127;
    int s5 = tid & 31, rh = tid >> 5;     // head role (tid<256): unit s5, row rh

    float b1j = b1[j], b2j = b2[j], b3o = b3[od];
    float w2s = shw2[s5], b1s = shb1[s5], b2s = shb2[0];
    float cum_r = 0.0f;

    const float4* w1q = (const float4*)w1p;
    const float4* w2q = (const float4*)w2p;
    const float4* w3q = (const float4*)w3p;
    const float4* w1hq = (const float4*)w1h;

    float* zA = bufA; float* zB = bufB;
    float* fP = bufFP; float* fN = bufFN;

    if (tid < 256) ((float4*)zA)[tid] = ((const float4*)(zinit + (size_t)blk * (ROWS * LL)))[tid];
    // pack head W1 [32][128] -> [k4][unit] float4 (conflict-free lane-s5 reads)
    for (int e = tid; e < 32 * 128; e += 512) {
        int u = e >> 7, k = e & 127;
        w1h[((k >> 2) * 32 + u) * 4 + (k & 3)] = shw1g[e];
    }
    __syncthreads();

    // f0 = f(z0, t=0)
    ode_f8(zA, hb1, hb2, fP, w1q, w2q, w3q, tembs, b1j, b2j, b3o, tid);

    const float Hh = 1.0f / (float)NS;

    for (int st = 0; st < NS; ++st) {
        float4 ka, zr0;
        if (tid < 256) {   // k1 = fP (FSAL)
            float4 f = ((const float4*)fP)[tid];
            zr0 = ((const float4*)zA)[tid];
            ka = f;
            ((float4*)ztl)[tid] = axpy4(0.5f * Hh, f, zr0);
        }
        __syncthreads();
        ode_f8(ztl, hb1, hb2, fN, w1q, w2q, w3q, tembs + (2 * st + 1) * 8, b1j, b2j, b3o, tid); // k2
        if (tid < 256) {
            float4 f = ((const float4*)fN)[tid];
            ka = axpy4(2.0f, f, ka);
            ((float4*)ztl)[tid] = axpy4(0.5f * Hh, f, zr0);
        }
        __syncthreads();
        ode_f8(ztl, hb1, hb2, fN, w1q, w2q, w3q, tembs + (2 * st + 1) * 8, b1j, b2j, b3o, tid); // k3
        if (tid < 256) {
            float4 f = ((const float4*)fN)[tid];
            ka = axpy4(2.0f, f, ka);
            ((float4*)ztl)[tid] = axpy4(Hh, f, zr0);
        }
        __syncthreads();
        ode_f8(ztl, hb1, hb2, fN, w1q, w2q, w3q, tembs + (2 * st + 2) * 8, b1j, b2j, b3o, tid); // k4
        if (tid < 256) {
            float4 f = ((const float4*)fN)[tid];
            float s6 = Hh / 6.0f;
            float4 kk = make_float4(ka.x + f.x, ka.y + f.y, ka.z + f.z, ka.w + f.w);
            ((float4*)zB)[tid] = axpy4(s6, kk, zr0);
        }
        __syncthreads();
        // f_{s+1} (next step's k1, and Hermite right-slope)
        ode_f8(zB, hb1, hb2, fN, w1q, w2q, w3q, tembs + (2 * st + 2) * 8, b1j, b2j, b3o, tid);

        // ---- emit head at output points inside [st/NS, (st+1)/NS] via Hermite ----
        int jlo = (47 * st + NS - 1) / NS;
        int jhi = (st == NS - 1) ? 47 : (47 * (st + 1) + NS - 1) / NS - 1;
        for (int jp = jlo; jp <= jhi; ++jp) {
            float th  = ((float)NS * (float)jp - 47.0f * (float)st) * (1.0f / 47.0f);
            float th2 = th * th, th3 = th2 * th;
            float c0 = 2.0f * th3 - 3.0f * th2 + 1.0f;
            float c1 = 3.0f * th2 - 2.0f * th3;
            float c2 = Hh * (th3 - 2.0f * th2 + th);
            float c3 = Hh * (th3 - th2);
            if (tid < 256) {
                float4 za = ((const float4*)zA)[tid];
                float4 zb = ((const float4*)zB)[tid];
                float4 fa = ((const float4*)fP)[tid];
                float4 fb = ((const float4*)fN)[tid];
                float4 zv;
                zv.x = c0*za.x + c1*zb.x + c2*fa.x + c3*fb.x;
                zv.y = c0*za.y + c1*zb.y + c2*fa.y + c3*fb.y;
                zv.z = c0*za.z + c1*zb.z + c2*fa.z + c3*fb.z;
                zv.w = c0*za.w + c1*zb.w + c2*fa.w + c3*fb.w;
                ((float4*)ztl)[tid] = zv;
            }
            __syncthreads();
            if (tid < 256) {
                float aa = b1s;
                const float4* zrow = (const float4*)(ztl + rh * LL);
                for (int k4 = 0; k4 < 32; ++k4) {
                    float4 w = w1hq[k4 * 32 + s5];
                    float4 v = zrow[k4];
                    aa = fmaf(w.x, v.x, aa); aa = fmaf(w.y, v.y, aa);
                    aa = fmaf(w.z, v.z, aa); aa = fmaf(w.w, v.w, aa);
                }
                float p = fmaxf(aa, 0.0f) * w2s;
                p += __shfl_xor(p, 1);  p += __shfl_xor(p, 2);
                p += __shfl_xor(p, 4);  p += __shfl_xor(p, 8);
                p += __shfl_xor(p, 16);
                float hz = sigm_f(p + b2s);
                float sv = __expf(cum_r);
                cum_r += __logf(1.0f - hz + 1e-7f);
                if (s5 == 0) {
                    int row = blk * ROWS + rh;
                    out_haz [row * NHZ + jp] = hz;
                    out_surv[row * NHZ + jp] = sv;
                    if (jp == NHZ - 1) out_pg[row] = 1.0f - sv;
                }
            }
            __syncthreads();
        }

        // roll buffers
        float* t0 = zA; zA = zB; zB = t0;
        t0 = fP; fP = fN; fN = t0;
    }
}

// ---------------- launch ----------------

extern "C" void kernel_launch(void* const* d_in, const int* in_sizes, int n_in,
                              void* d_out, int out_size, void* d_ws, size_t ws_size,
                              hipStream_t stream) {
    const float* X        = (const float*)d_in[0];
    const float* Mask     = (const float*)d_in[1];
    const float* gru_w_ih = (const float*)d_in[2];
    const float* gru_w_hh = (const float*)d_in[3];
    const float* gru_b_ih = (const float*)d_in[4];
    const float* gru_b_hh = (const float*)d_in[5];
    const float* z0_w     = (const float*)d_in[6];
    const float* z0_b     = (const float*)d_in[7];
    const float* tproj_w  = (const float*)d_in[8];
    const float* tproj_b  = (const float*)d_in[9];
    const float* ode_w1   = (const float*)d_in[10];
    const float* ode_b1   = (const float*)d_in[11];
    const float* ode_w2   = (const float*)d_in[12];
    const float* ode_b2   = (const float*)d_in[13];
    const float* ode_w3   = (const float*)d_in[14];
    const float* ode_b3   = (const float*)d_in[15];
    const float* sh_w1    = (const float*)d_in[16];
    const float* sh_b1    = (const float*)d_in[17];
    const float* sh_w2    = (const float*)d_in[18];
    const float* sh_b2    = (const float*)d_in[19];

    float* ws    = (float*)d_ws;
    float* w_ihp = ws;                    // 64*768    = 49152
    float* w_hhp = w_ihp + 49152;         // 256*768   = 196608
    float* z0_wp = w_hhp + 196608;        // 256*256   = 65536
    float* w1p   = z0_wp + 65536;         // 136*256   = 34816
    float* w2p   = w1p   + 34816;         // 256*256   = 65536
    float* w3p   = w2p   + 65536;         // 256*128   = 32768
    float* tembs = w3p   + 32768;         // 25*8      = 200

    float* out      = (float*)d_out;
    float* out_haz  = out;                              // 4096*48
    float* out_surv = out + 196608;                     // 4096*48
    float* out_mean = out + 393216;                     // 4096*128
    float* out_lv   = out + 917504;                     // 4096*128
    float* out_pg   = out + 1441792;                    // 4096

    pack4_k<<<(768*64  + 255) / 256, 256, 0, stream>>>(gru_w_ih, w_ihp, 768, 64);
    pack4_k<<<(768*256 + 255) / 256, 256, 0, stream>>>(gru_w_hh, w_hhp, 768, 256);
    pack4_k<<<(256*256 + 255) / 256, 256, 0, stream>>>(z0_w,     z0_wp, 256, 256);
    pack4_k<<<(256*136 + 255) / 256, 256, 0, stream>>>(ode_w1,   w1p,   256, 136);
    pack4_k<<<(256*256 + 255) / 256, 256, 0, stream>>>(ode_w2,   w2p,   256, 256);
    pack4_k<<<(128*256 + 255) / 256, 256, 0, stream>>>(ode_w3,   w3p,   128, 256);
    temb_k<<<1, 64, 0, stream>>>(tproj_w, tproj_b, tembs);

    gru_k<<<BB / ROWS, 512, 0, stream>>>(X, Mask, w_ihp, w_hhp, gru_b_ih, gru_b_hh,
                                         z0_wp, z0_b, out_mean, out_lv);

    ode_head_k<<<BB / ROWS, 512, 0, stream>>>(out_mean, w1p, w2p, w3p,
                                              ode_b1, ode_b2, ode_b3, tembs,
                                              sh_w1, sh_b1, sh_w2, sh_b2,
                                              out_haz, out_surv, out_pg);
}

// Round 8
// 2425.143 us; speedup vs baseline: 9.3358x; 9.3358x over previous
//
#include <hip/hip_runtime.h>
#include <math.h>

#define BB 4096
#define TT 48
#define DD 32
#define HH 256
#define LL 128
#define HID 256
#define EE 8
#define NHZ 48
#define NS 8              // RK4 macro steps (dense-output Hermite between knots)
#define NTEMB (2*NS+1)    // 17 precomputed time-embeddings (knots + midpoints)

__device__ __forceinline__ float sigm_f(float x) {
    return 1.0f / (1.0f + __expf(-x));
}
__device__ __forceinline__ float tanh_f(float x) {
    x = fminf(fmaxf(x, -15.0f), 15.0f);
    float e = __expf(2.0f * x);
    return (e - 1.0f) / (e + 1.0f);
}
__device__ __forceinline__ float4 axpy4(float s, float4 a, float4 z) {
    return make_float4(fmaf(s, a.x, z.x), fmaf(s, a.y, z.y),
                       fmaf(s, a.z, z.z), fmaf(s, a.w, z.w));
}

// ---------------- prep kernels ----------------
// pack4: src [OUT][IN] row-major -> dst[(k>>2)*OUT + o] float4 = w[o][4k..4k+3]

__global__ void pack4_k(const float* __restrict__ src, float* __restrict__ dst, int OUT, int IN) {
    int i = blockIdx.x * 256 + threadIdx.x;
    if (i < OUT * IN) {
        int o = i / IN, k = i % IN;
        dst[((k >> 2) * OUT + o) * 4 + (k & 3)] = src[i];
    }
}

__global__ void temb_k(const float* __restrict__ tproj_w, const float* __restrict__ tproj_b,
                       float* __restrict__ tembs) {
    int i = blockIdx.x * 64 + threadIdx.x;
    if (i >= NTEMB) return;
    float t = (float)i / (float)(2 * NS);
    const float PI = 3.14159265358979323846f;
    float emb[8];
    #pragma unroll
    for (int m = 0; m < 4; ++m) {
        float pos = t * (float)(m + 1) * PI;
        emb[m]     = sinf(pos);
        emb[4 + m] = cosf(pos);
    }
    #pragma unroll
    for (int o = 0; o < 8; ++o) {
        float a = tproj_b[o];
        #pragma unroll
        for (int k = 0; k < 8; ++k) a = fmaf(tproj_w[o * 8 + k], emb[k], a);
        tembs[i * 8 + o] = a;
    }
}

// ---------------- GRU encoder (+ fused z0 projection) ----------------
// ROUND-4 EXACT (proven 1.15ms, no spills): 16 rows/block, 512 threads,
// grid 256 (1 block/CU -> weights L2/L3-resident). j = tid&255 owns gate
// triplet col j; half = tid>>8 owns rows half*8..+7.

__global__ __launch_bounds__(512, 2) void gru_k(
    const float* __restrict__ Xp, const float* __restrict__ Mp,
    const float* __restrict__ w_ihp,   // packed [16][768][4]
    const float* __restrict__ w_hhp,   // packed [64][768][4]
    const float* __restrict__ b_ih, const float* __restrict__ b_hh,
    const float* __restrict__ z0_wp,   // packed [64][256][4]
    const float* __restrict__ z0_b,
    float* __restrict__ out_mean, float* __restrict__ out_lv) {

    __shared__ __align__(16) float h[16 * HH];   // 16KB
    __shared__ __align__(16) float u[16 * 64];   // 4KB
    __shared__ float obs[16];

    int tid = threadIdx.x, blk = blockIdx.x;
    int j = tid & 255, rb = (tid >> 8) * 8;

    const float4* hq  = (const float4*)h;
    const float4* uq  = (const float4*)u;
    const float4* wih = (const float4*)w_ihp;
    const float4* whh = (const float4*)w_hhp;
    const float4* z0q = (const float4*)z0_wp;

    for (int e = tid; e < 16 * HH; e += 512) h[e] = 0.0f;

    float brz0 = b_ih[j]       + b_hh[j];
    float brz1 = b_ih[256 + j] + b_hh[256 + j];
    float bin_ = b_ih[512 + j];
    float bhn_ = b_hh[512 + j];
    __syncthreads();

    for (int t = TT - 1; t >= 0; --t) {
        if (tid < 256) {
            int r = tid >> 4, c4 = tid & 15;
            const float* base = (c4 < 8 ? Xp : Mp) + (size_t)(blk * 16 + r) * (TT * DD) + t * DD;
            ((float4*)u)[tid] = ((const float4*)base)[c4 & 7];
        }
        __syncthreads();
        if (tid < 16) {
            float sm = 0.0f;
            #pragma unroll
            for (int i = 8; i < 16; ++i) {
                float4 v = uq[tid * 16 + i];
                sm += v.x + v.y + v.z + v.w;
            }
            obs[tid] = (sm > 0.0f) ? 1.0f : 0.0f;
        }

        float ar[8], az[8], an[8], ah[8];
        #pragma unroll
        for (int r = 0; r < 8; ++r) { ar[r] = brz0; az[r] = brz1; an[r] = bin_; ah[r] = bhn_; }

        // input contribution: 16 packed k4 over 64 inputs
        for (int k4 = 0; k4 < 16; ++k4) {
            float4 wr = wih[k4 * 768 + j];
            float4 wz = wih[k4 * 768 + 256 + j];
            float4 wn = wih[k4 * 768 + 512 + j];
            #pragma unroll
            for (int r = 0; r < 8; ++r) {
                float4 v = uq[(rb + r) * 16 + k4];
                ar[r] = fmaf(wr.x, v.x, ar[r]); az[r] = fmaf(wz.x, v.x, az[r]); an[r] = fmaf(wn.x, v.x, an[r]);
                ar[r] = fmaf(wr.y, v.y, ar[r]); az[r] = fmaf(wz.y, v.y, az[r]); an[r] = fmaf(wn.y, v.y, an[r]);
                ar[r] = fmaf(wr.z, v.z, ar[r]); az[r] = fmaf(wz.z, v.z, az[r]); an[r] = fmaf(wn.z, v.z, an[r]);
                ar[r] = fmaf(wr.w, v.w, ar[r]); az[r] = fmaf(wz.w, v.w, az[r]); an[r] = fmaf(wn.w, v.w, an[r]);
            }
        }
        // hidden contribution: 64 packed k4 over 256
        for (int k4 = 0; k4 < 64; ++k4) {
            float4 wr = whh[k4 * 768 + j];
            float4 wz = whh[k4 * 768 + 256 + j];
            float4 wn = whh[k4 * 768 + 512 + j];
            #pragma unroll
            for (int r = 0; r < 8; ++r) {
                float4 v = hq[(rb + r) * 64 + k4];
                ar[r] = fmaf(wr.x, v.x, ar[r]); az[r] = fmaf(wz.x, v.x, az[r]); ah[r] = fmaf(wn.x, v.x, ah[r]);
                ar[r] = fmaf(wr.y, v.y, ar[r]); az[r] = fmaf(wz.y, v.y, az[r]); ah[r] = fmaf(wn.y, v.y, ah[r]);
                ar[r] = fmaf(wr.z, v.z, ar[r]); az[r] = fmaf(wz.z, v.z, az[r]); ah[r] = fmaf(wn.z, v.z, ah[r]);
                ar[r] = fmaf(wr.w, v.w, ar[r]); az[r] = fmaf(wz.w, v.w, az[r]); ah[r] = fmaf(wn.w, v.w, ah[r]);
            }
        }

        float hnew[8], hold[8];
        #pragma unroll
        for (int r = 0; r < 8; ++r) {
            float rg = sigm_f(ar[r]);
            float zg = sigm_f(az[r]);
            float n  = tanh_f(an[r] + rg * ah[r]);
            float hv = h[(rb + r) * HH + j];
            hold[r] = hv;
            hnew[r] = (1.0f - zg) * n + zg * hv;
        }
        __syncthreads();
        #pragma unroll
        for (int r = 0; r < 8; ++r) {
            float o = obs[rb + r];
            h[(rb + r) * HH + j] = o * hnew[r] + (1.0f - o) * hold[r];
        }
        __syncthreads();
    }

    // fused z0 projection
    float zr_[8];
    #pragma unroll
    for (int r = 0; r < 8; ++r) zr_[r] = z0_b[j];
    for (int k4 = 0; k4 < 64; ++k4) {
        float4 w = z0q[k4 * 256 + j];
        #pragma unroll
        for (int r = 0; r < 8; ++r) {
            float4 v = hq[(rb + r) * 64 + k4];
            zr_[r] = fmaf(w.x, v.x, zr_[r]);
            zr_[r] = fmaf(w.y, v.y, zr_[r]);
            zr_[r] = fmaf(w.z, v.z, zr_[r]);
            zr_[r] = fmaf(w.w, v.w, zr_[r]);
        }
    }
    int row0 = blk * 16 + rb;
    if (j < 128) {
        #pragma unroll
        for (int r = 0; r < 8; ++r) out_mean[(row0 + r) * LL + j] = zr_[r];
    } else {
        #pragma unroll
        for (int r = 0; r < 8; ++r) out_lv[(row0 + r) * LL + (j - 128)] = zr_[r];
    }
}

// ---------------- ODE dynamics eval: 512 threads, 16 rows ----------------
// Separate h1/h2 buffers: 3 barriers per eval instead of 4.

__device__ __forceinline__ void ode_f512(
    const float* __restrict__ in, float* __restrict__ h1, float* __restrict__ h2,
    float* __restrict__ out,
    const float4* __restrict__ w1q, const float4* __restrict__ w2q, const float4* __restrict__ w3q,
    const float* __restrict__ temb,   // 8 floats (global, L2)
    float b1j, float b2j, float b3o, int tid) {

    int j  = tid & 255;  int rb = (tid >> 8) * 8;   // phases A,B: 8 rows
    int od = tid & 127;  int rc = (tid >> 7) * 4;   // phase C: 4 rows

    const float4* inq = (const float4*)in;
    const float4* h1q = (const float4*)h1;
    const float4* h2q = (const float4*)h2;

    // phase A: h1 = tanh([z,temb] @ w1.T + b1)
    float4 wt0 = w1q[32 * 256 + j];
    float4 wt1 = w1q[33 * 256 + j];
    float tacc = b1j;
    tacc = fmaf(wt0.x, temb[0], tacc); tacc = fmaf(wt0.y, temb[1], tacc);
    tacc = fmaf(wt0.z, temb[2], tacc); tacc = fmaf(wt0.w, temb[3], tacc);
    tacc = fmaf(wt1.x, temb[4], tacc); tacc = fmaf(wt1.y, temb[5], tacc);
    tacc = fmaf(wt1.z, temb[6], tacc); tacc = fmaf(wt1.w, temb[7], tacc);
    float a[8];
    #pragma unroll
    for (int r = 0; r < 8; ++r) a[r] = tacc;
    for (int k4 = 0; k4 < 32; ++k4) {
        float4 w = w1q[k4 * 256 + j];
        #pragma unroll
        for (int r = 0; r < 8; ++r) {
            float4 v = inq[(rb + r) * 32 + k4];
            a[r] = fmaf(w.x, v.x, a[r]); a[r] = fmaf(w.y, v.y, a[r]);
            a[r] = fmaf(w.z, v.z, a[r]); a[r] = fmaf(w.w, v.w, a[r]);
        }
    }
    #pragma unroll
    for (int r = 0; r < 8; ++r) h1[(rb + r) * HID + j] = tanh_f(a[r]);
    __syncthreads();

    // phase B: h2 = tanh(h1 @ w2.T + b2)  (separate buffer -> no WAR barrier)
    float c[8];
    #pragma unroll
    for (int r = 0; r < 8; ++r) c[r] = b2j;
    for (int k4 = 0; k4 < 64; ++k4) {
        float4 w = w2q[k4 * 256 + j];
        #pragma unroll
        for (int r = 0; r < 8; ++r) {
            float4 v = h1q[(rb + r) * 64 + k4];
            c[r] = fmaf(w.x, v.x, c[r]); c[r] = fmaf(w.y, v.y, c[r]);
            c[r] = fmaf(w.z, v.z, c[r]); c[r] = fmaf(w.w, v.w, c[r]);
        }
    }
    #pragma unroll
    for (int r = 0; r < 8; ++r) h2[(rb + r) * HID + j] = tanh_f(c[r]);
    __syncthreads();

    // phase C: out = h2 @ w3.T + b3 (4 rows per thread at out-dim od)
    float d[4];
    #pragma unroll
    for (int r = 0; r < 4; ++r) d[r] = b3o;
    for (int k4 = 0; k4 < 64; ++k4) {
        float4 w = w3q[k4 * 128 + od];
        #pragma unroll
        for (int r = 0; r < 4; ++r) {
            float4 v = h2q[(rc + r) * 64 + k4];
            d[r] = fmaf(w.x, v.x, d[r]); d[r] = fmaf(w.y, v.y, d[r]);
            d[r] = fmaf(w.z, v.z, d[r]); d[r] = fmaf(w.w, v.w, d[r]);
        }
    }
    #pragma unroll
    for (int r = 0; r < 4; ++r) out[(rc + r) * LL + od] = d[r];
    __syncthreads();
}

// ---------------- ODE (8-step RK4 + Hermite dense output) + head ----------------
// Round-4 launch geometry (grid 256, 512 thr, (512,2)); LDS 88KB, 1 block/CU.

__global__ __launch_bounds__(512, 2) void ode_head_k(
    const float* __restrict__ zinit,
    const float* __restrict__ w1p, const float* __restrict__ w2p, const float* __restrict__ w3p,
    const float* __restrict__ b1, const float* __restrict__ b2, const float* __restrict__ b3,
    const float* __restrict__ tembs,
    const float* __restrict__ shw1g, const float* __restrict__ shb1,
    const float* __restrict__ shw2, const float* __restrict__ shb2,
    float* __restrict__ out_haz, float* __restrict__ out_surv, float* __restrict__ out_pg) {

    __shared__ __align__(16) float bufA [16 * LL];   // 8KB  (z at knot s)
    __shared__ __align__(16) float bufB [16 * LL];   // 8KB  (z at knot s+1)
    __shared__ __align__(16) float bufFP[16 * LL];   // 8KB  (f at knot s)
    __shared__ __align__(16) float bufFN[16 * LL];   // 8KB  (f at knot s+1 / scratch)
    __shared__ __align__(16) float ztl  [16 * LL];   // 8KB  (stage state / z-theta)
    __shared__ __align__(16) float hb1  [16 * HID];  // 16KB
    __shared__ __align__(16) float hb2  [16 * HID];  // 16KB
    __shared__ __align__(16) float w1h  [32 * 128];  // 16KB head W1 packed [k4][unit][4]

    int tid = threadIdx.x, blk = blockIdx.x;
    int j = tid & 255, od = tid & 127;
    int s5 = tid & 31, rh = tid >> 5;     // head role: unit s5, row rh (all 512 threads)

    float b1j = b1[j], b2j = b2[j], b3o = b3[od];
    float w2s = shw2[s5], b1s = shb1[s5], b2s = shb2[0];
    float cum_r = 0.0f;

    const float4* w1q = (const float4*)w1p;
    const float4* w2q = (const float4*)w2p;
    const float4* w3q = (const float4*)w3p;
    const float4* w1hq = (const float4*)w1h;

    float* zA = bufA; float* zB = bufB;
    float* fP = bufFP; float* fN = bufFN;

    ((float4*)zA)[tid] = ((const float4*)(zinit + (size_t)blk * 2048))[tid];
    // pack head W1 [32][128] -> [k4][unit] float4 (conflict-free lane-s5 reads)
    for (int e = tid; e < 32 * 128; e += 512) {
        int u = e >> 7, k = e & 127;
        w1h[((k >> 2) * 32 + u) * 4 + (k & 3)] = shw1g[e];
    }
    __syncthreads();

    // f0 = f(z0, t=0)
    ode_f512(zA, hb1, hb2, fP, w1q, w2q, w3q, tembs, b1j, b2j, b3o, tid);

    const float Hh = 1.0f / (float)NS;

    for (int st = 0; st < NS; ++st) {
        float4 ka, zr0;
        {   // k1 = fP (FSAL)
            float4 f = ((const float4*)fP)[tid];
            zr0 = ((const float4*)zA)[tid];
            ka = f;
            ((float4*)ztl)[tid] = axpy4(0.5f * Hh, f, zr0);
        }
        __syncthreads();
        ode_f512(ztl, hb1, hb2, fN, w1q, w2q, w3q, tembs + (2 * st + 1) * 8, b1j, b2j, b3o, tid); // k2
        {
            float4 f = ((const float4*)fN)[tid];
            ka = axpy4(2.0f, f, ka);
            ((float4*)ztl)[tid] = axpy4(0.5f * Hh, f, zr0);
        }
        __syncthreads();
        ode_f512(ztl, hb1, hb2, fN, w1q, w2q, w3q, tembs + (2 * st + 1) * 8, b1j, b2j, b3o, tid); // k3
        {
            float4 f = ((const float4*)fN)[tid];
            ka = axpy4(2.0f, f, ka);
            ((float4*)ztl)[tid] = axpy4(Hh, f, zr0);
        }
        __syncthreads();
        ode_f512(ztl, hb1, hb2, fN, w1q, w2q, w3q, tembs + (2 * st + 2) * 8, b1j, b2j, b3o, tid); // k4
        {
            float4 f = ((const float4*)fN)[tid];
            float s6 = Hh / 6.0f;
            float4 kk = make_float4(ka.x + f.x, ka.y + f.y, ka.z + f.z, ka.w + f.w);
            ((float4*)zB)[tid] = axpy4(s6, kk, zr0);
        }
        __syncthreads();
        // f_{s+1} (next step's k1, and Hermite right-slope)
        ode_f512(zB, hb1, hb2, fN, w1q, w2q, w3q, tembs + (2 * st + 2) * 8, b1j, b2j, b3o, tid);

        // ---- emit head at output points inside [st/NS, (st+1)/NS] via Hermite ----
        int jlo = (47 * st + NS - 1) / NS;
        int jhi = (st == NS - 1) ? 47 : (47 * (st + 1) + NS - 1) / NS - 1;
        for (int jp = jlo; jp <= jhi; ++jp) {
            float th  = ((float)NS * (float)jp - 47.0f * (float)st) * (1.0f / 47.0f);
            float th2 = th * th, th3 = th2 * th;
            float c0 = 2.0f * th3 - 3.0f * th2 + 1.0f;
            float c1 = 3.0f * th2 - 2.0f * th3;
            float c2 = Hh * (th3 - 2.0f * th2 + th);
            float c3 = Hh * (th3 - th2);
            {
                float4 za = ((const float4*)zA)[tid];
                float4 zb = ((const float4*)zB)[tid];
                float4 fa = ((const float4*)fP)[tid];
                float4 fb = ((const float4*)fN)[tid];
                float4 zv;
                zv.x = c0*za.x + c1*zb.x + c2*fa.x + c3*fb.x;
                zv.y = c0*za.y + c1*zb.y + c2*fa.y + c3*fb.y;
                zv.z = c0*za.z + c1*zb.z + c2*fa.z + c3*fb.z;
                zv.w = c0*za.w + c1*zb.w + c2*fa.w + c3*fb.w;
                ((float4*)ztl)[tid] = zv;
            }
            __syncthreads();
            {
                float aa = b1s;
                const float4* zrow = (const float4*)(ztl + rh * LL);
                for (int k4 = 0; k4 < 32; ++k4) {
                    float4 w = w1hq[k4 * 32 + s5];
                    float4 v = zrow[k4];
                    aa = fmaf(w.x, v.x, aa); aa = fmaf(w.y, v.y, aa);
                    aa = fmaf(w.z, v.z, aa); aa = fmaf(w.w, v.w, aa);
                }
                float p = fmaxf(aa, 0.0f) * w2s;
                p += __shfl_xor(p, 1);  p += __shfl_xor(p, 2);
                p += __shfl_xor(p, 4);  p += __shfl_xor(p, 8);
                p += __shfl_xor(p, 16);
                float hz = sigm_f(p + b2s);
                float sv = __expf(cum_r);
                cum_r += __logf(1.0f - hz + 1e-7f);
                if (s5 == 0) {
                    int row = blk * 16 + rh;
                    out_haz [row * NHZ + jp] = hz;
                    out_surv[row * NHZ + jp] = sv;
                    if (jp == NHZ - 1) out_pg[row] = 1.0f - sv;
                }
            }
            __syncthreads();
        }

        // roll buffers
        float* t0 = zA; zA = zB; zB = t0;
        t0 = fP; fP = fN; fN = t0;
    }
}

// ---------------- launch ----------------

extern "C" void kernel_launch(void* const* d_in, const int* in_sizes, int n_in,
                              void* d_out, int out_size, void* d_ws, size_t ws_size,
                              hipStream_t stream) {
    const float* X        = (const float*)d_in[0];
    const float* Mask     = (const float*)d_in[1];
    const float* gru_w_ih = (const float*)d_in[2];
    const float* gru_w_hh = (const float*)d_in[3];
    const float* gru_b_ih = (const float*)d_in[4];
    const float* gru_b_hh = (const float*)d_in[5];
    const float* z0_w     = (const float*)d_in[6];
    const float* z0_b     = (const float*)d_in[7];
    const float* tproj_w  = (const float*)d_in[8];
    const float* tproj_b  = (const float*)d_in[9];
    const float* ode_w1   = (const float*)d_in[10];
    const float* ode_b1   = (const float*)d_in[11];
    const float* ode_w2   = (const float*)d_in[12];
    const float* ode_b2   = (const float*)d_in[13];
    const float* ode_w3   = (const float*)d_in[14];
    const float* ode_b3   = (const float*)d_in[15];
    const float* sh_w1    = (const float*)d_in[16];
    const float* sh_b1    = (const float*)d_in[17];
    const float* sh_w2    = (const float*)d_in[18];
    const float* sh_b2    = (const float*)d_in[19];

    float* ws    = (float*)d_ws;
    float* w_ihp = ws;                    // 64*768    = 49152
    float* w_hhp = w_ihp + 49152;         // 256*768   = 196608
    float* z0_wp = w_hhp + 196608;        // 256*256   = 65536
    float* w1p   = z0_wp + 65536;         // 136*256   = 34816
    float* w2p   = w1p   + 34816;         // 256*256   = 65536
    float* w3p   = w2p   + 65536;         // 256*128   = 32768
    float* tembs = w3p   + 32768;         // 17*8      = 136

    float* out      = (float*)d_out;
    float* out_haz  = out;                              // 4096*48
    float* out_surv = out + 196608;                     // 4096*48
    float* out_mean = out + 393216;                     // 4096*128
    float* out_lv   = out + 917504;                     // 4096*128
    float* out_pg   = out + 1441792;                    // 4096

    pack4_k<<<(768*64  + 255) / 256, 256, 0, stream>>>(gru_w_ih, w_ihp, 768, 64);
    pack4_k<<<(768*256 + 255) / 256, 256, 0, stream>>>(gru_w_hh, w_hhp, 768, 256);
    pack4_k<<<(256*256 + 255) / 256, 256, 0, stream>>>(z0_w,     z0_wp, 256, 256);
    pack4_k<<<(256*136 + 255) / 256, 256, 0, stream>>>(ode_w1,   w1p,   256, 136);
    pack4_k<<<(256*256 + 255) / 256, 256, 0, stream>>>(ode_w2,   w2p,   256, 256);
    pack4_k<<<(128*256 + 255) / 256, 256, 0, stream>>>(ode_w3,   w3p,   128, 256);
    temb_k<<<1, 64, 0, stream>>>(tproj_w, tproj_b, tembs);

    gru_k<<<BB / 16, 512, 0, stream>>>(X, Mask, w_ihp, w_hhp, gru_b_ih, gru_b_hh,
                                       z0_wp, z0_b, out_mean, out_lv);

    ode_head_k<<<BB / 16, 512, 0, stream>>>(out_mean, w1p, w2p, w3p,
                                            ode_b1, ode_b2, ode_b3, tembs,
                                            sh_w1, sh_b1, sh_w2, sh_b2,
                                            out_haz, out_surv, out_pg);
}